// Round 10
// baseline (124.564 us; speedup 1.0000x reference)
//
#include <hip/hip_runtime.h>
#include <math.h>

#define DI 1024   // model dim
#define SQ 2048   // sequence length
#define NB 2      // batch
#define NH 16     // heads
#define HD 64     // head dim
#define QSCALE 0.18033688f   // 0.125 * log2(e): folded into Q so softmax exp is raw v_exp_f32 (2^x)

typedef __attribute__((ext_vector_type(8))) short short8;
typedef __attribute__((ext_vector_type(4))) float f32x4;
typedef __attribute__((ext_vector_type(16))) float f32x16;
typedef __attribute__((ext_vector_type(2))) unsigned int uint2v;
typedef __attribute__((ext_vector_type(4))) int int4v;
typedef __attribute__((ext_vector_type(4))) unsigned short ushort4v;

static __device__ __forceinline__ unsigned short f2bf(float f) {
    union { float f; unsigned u; } v; v.f = f;
    unsigned r = v.u + 0x7FFFu + ((v.u >> 16) & 1u);  // RNE
    return (unsigned short)(r >> 16);
}
static __device__ __forceinline__ float bf2f(unsigned short b) {
    union { unsigned u; float f; } v; v.u = ((unsigned)b) << 16; return v.f;
}
static __device__ __forceinline__ float fexp2(float x) {
    float r; asm("v_exp_f32 %0, %1" : "=v"(r) : "v"(x)); return r;
}
static __device__ __forceinline__ unsigned cvtpk(float lo, float hi) {
    unsigned r; asm("v_cvt_pk_bf16_f32 %0, %1, %2" : "=v"(r) : "v"(lo), "v"(hi)); return r;
}
static __device__ __forceinline__ void plswap(unsigned& a, unsigned& b) {
    asm volatile("v_permlane32_swap_b32 %0, %1" : "+v"(a), "+v"(b));
}
static __device__ __forceinline__ short8 pack4(unsigned a, unsigned b, unsigned c, unsigned d) {
    union { unsigned u[4]; short8 s; } x; x.u[0] = a; x.u[1] = b; x.u[2] = c; x.u[3] = d; return x.s;
}

typedef __attribute__((address_space(1))) const unsigned int gas_uint;
typedef __attribute__((address_space(3))) unsigned int las_uint;
static __device__ __forceinline__ void gload16(const void* g, void* l) {
    __builtin_amdgcn_global_load_lds((gas_uint*)g, (las_uint*)l, 16, 0, 0);
}
#define RAW_BARRIER() do { __builtin_amdgcn_s_barrier(); \
                           __builtin_amdgcn_sched_barrier(0); } while (0)
#define WAIT_VM4()  do { asm volatile("s_waitcnt vmcnt(4)" ::: "memory"); \
                         __builtin_amdgcn_sched_barrier(0); } while (0)
#define WAIT_VM0()  do { asm volatile("s_waitcnt vmcnt(0)" ::: "memory"); \
                         __builtin_amdgcn_sched_barrier(0); } while (0)

#define MFMA16(a, b, c) __builtin_amdgcn_mfma_f32_16x16x32_bf16(a, b, c, 0, 0, 0)
#define MFMA32(a, b, c) __builtin_amdgcn_mfma_f32_32x32x16_bf16(a, b, c, 0, 0, 0)

// ---------------------------------------------------------------- cvt x -> bf16
__global__ __launch_bounds__(256) void k_cvt_bf16(const float* __restrict__ src,
                                                  unsigned short* __restrict__ dst) {
    int i = blockIdx.x * 256 + threadIdx.x;     // 8 floats / thread
    const f32x4* s4 = (const f32x4*)src + (size_t)i * 2;
    f32x4 a = s4[0], b = s4[1];
    ushort4v o0, o1;
    o0[0] = f2bf(a[0]); o0[1] = f2bf(a[1]); o0[2] = f2bf(a[2]); o0[3] = f2bf(a[3]);
    o1[0] = f2bf(b[0]); o1[1] = f2bf(b[1]); o1[2] = f2bf(b[2]); o1[3] = f2bf(b[3]);
    *(ushort4v*)(dst + (size_t)i * 8)     = o0;
    *(ushort4v*)(dst + (size_t)i * 8 + 4) = o1;
}

// ------------------------------------- 4x: W [K][N] f32 -> Wt [N][K] bf16 (one dispatch)
__global__ __launch_bounds__(256) void k_transpose_w4(const float* __restrict__ W0, const float* __restrict__ W1,
                                                      const float* __restrict__ W2, const float* __restrict__ W3,
                                                      unsigned short* __restrict__ T0, unsigned short* __restrict__ T1,
                                                      unsigned short* __restrict__ T2, unsigned short* __restrict__ T3) {
    const float* W; unsigned short* T;
    switch (blockIdx.z) {
        case 0: W = W0; T = T0; break;
        case 1: W = W1; T = T1; break;
        case 2: W = W2; T = T2; break;
        default: W = W3; T = T3; break;
    }
    __shared__ float t[32][33];
    int tx = threadIdx.x, ty = threadIdx.y;     // block (32,8)
    int n0 = blockIdx.x * 32, k0 = blockIdx.y * 32;
#pragma unroll
    for (int j = 0; j < 32; j += 8) t[ty + j][tx] = W[(size_t)(k0 + ty + j) * DI + n0 + tx];
    __syncthreads();
#pragma unroll
    for (int j = 0; j < 32; j += 8)
        T[(size_t)(n0 + ty + j) * DI + k0 + tx] = f2bf(t[tx][ty + j]);
}

// ---------------------------------------------------------------- NT GEMM (m97 + counted vmcnt, 3-buf)
// MODE 0: fused QKV. Bt = [3*1024][1024]; which = tn>>3 routes to oK / oQ(scaled) / oV(transposed).
// MODE 2: f32 out + bias (final projection), C = oK as float*.
template <int MODE>
__global__ __launch_bounds__(256) void k_gemm(const unsigned short* __restrict__ A,
                                              const unsigned short* __restrict__ Bt,
                                              unsigned short* __restrict__ oK,
                                              unsigned short* __restrict__ oQ,
                                              unsigned short* __restrict__ oV,
                                              const float* __restrict__ bias) {
    __shared__ __align__(16) unsigned short As[3][128 * 32];   // linear, 64B rows, 3-buf
    __shared__ __align__(16) unsigned short Bs[3][128 * 32];
    const int tid = threadIdx.x, lane = tid & 63, w = tid >> 6;
    const int wr = w >> 1, wc = w & 1;
    const int tm = blockIdx.y, tn = blockIdx.x;
    const unsigned short* Abase = A  + (size_t)tm * 128 * DI;
    const unsigned short* Bbase = Bt + (size_t)tn * 128 * DI;

    auto stage = [&](int kt, int bi) {          // 4 global_load_lds per thread
#pragma unroll
        for (int i = 0; i < 2; ++i) {
            int u = tid + i * 256;              // 0..511 : row = u>>2, 16B seg = u&3
            int row = u >> 2, c8 = (u & 3) * 8;
            gload16(Abase + (size_t)row * DI + kt * 32 + c8, &As[bi][u * 8]);
            gload16(Bbase + (size_t)row * DI + kt * 32 + c8, &Bs[bi][u * 8]);
        }
    };

    f32x4 acc[4][4] = {};
    stage(0, 0);
    for (int kt = 0; kt < DI / 32; ++kt) {
        if (kt + 1 < DI / 32) { stage(kt + 1, (kt + 1) % 3); WAIT_VM4(); }
        else                  { WAIT_VM0(); }
        RAW_BARRIER();                          // all waves' tile-kt loads landed
        const int bi = kt % 3;
        short8 af[4], bf[4];
#pragma unroll
        for (int mi = 0; mi < 4; ++mi)
            af[mi] = *(const short8*)&As[bi][(wr * 64 + mi * 16 + (lane & 15)) * 32 + (lane >> 4) * 8];
#pragma unroll
        for (int ni = 0; ni < 4; ++ni)
            bf[ni] = *(const short8*)&Bs[bi][(wc * 64 + ni * 16 + (lane & 15)) * 32 + (lane >> 4) * 8];
        __builtin_amdgcn_s_setprio(1);
#pragma unroll
        for (int mi = 0; mi < 4; ++mi)
#pragma unroll
            for (int ni = 0; ni < 4; ++ni)
                acc[mi][ni] = MFMA16(af[mi], bf[ni], acc[mi][ni]);
        __builtin_amdgcn_s_setprio(0);
    }

    if (MODE == 2) {
        float bv[4];
#pragma unroll
        for (int ni = 0; ni < 4; ++ni) bv[ni] = bias[tn * 128 + wc * 64 + ni * 16 + (lane & 15)];
        float* Co = (float*)oK;
#pragma unroll
        for (int mi = 0; mi < 4; ++mi)
#pragma unroll
            for (int ni = 0; ni < 4; ++ni)
#pragma unroll
                for (int j = 0; j < 4; ++j) {
                    int m = tm * 128 + wr * 64 + mi * 16 + (lane >> 4) * 4 + j;
                    int n = tn * 128 + wc * 64 + ni * 16 + (lane & 15);
                    Co[(size_t)m * DI + n] = acc[mi][ni][j] + bv[ni];
                }
    } else {
        const int which = tn >> 3;                  // 0:K  1:Q(scaled)  2:V(transposed)
        if (which < 2) {
            unsigned short* Co = which ? oQ : oK;
            const float scl = which ? QSCALE : 1.0f;
#pragma unroll
            for (int mi = 0; mi < 4; ++mi)
#pragma unroll
                for (int ni = 0; ni < 4; ++ni)
#pragma unroll
                    for (int j = 0; j < 4; ++j) {
                        int m = tm * 128 + wr * 64 + mi * 16 + (lane >> 4) * 4 + j;
                        int n = (tn & 7) * 128 + wc * 64 + ni * 16 + (lane & 15);
                        Co[(((size_t)(m >> 11) * NH + (n >> 6)) * SQ + (m & 2047)) * HD + (n & 63)] =
                            f2bf(acc[mi][ni][j] * scl);
                    }
        } else {                                    // V^T: [B][H][D][S], 4 S-contig per lane
#pragma unroll
            for (int mi = 0; mi < 4; ++mi)
#pragma unroll
                for (int ni = 0; ni < 4; ++ni) {
                    uint2v pk;
                    pk[0] = cvtpk(acc[mi][ni][0], acc[mi][ni][1]);
                    pk[1] = cvtpk(acc[mi][ni][2], acc[mi][ni][3]);
                    int m = tm * 128 + wr * 64 + mi * 16 + (lane >> 4) * 4;
                    int n = (tn & 7) * 128 + wc * 64 + ni * 16 + (lane & 15);
                    *(uint2v*)&oV[(((size_t)(m >> 11) * NH + (n >> 6)) * HD + (n & 63)) * SQ + (m & 2047)] = pk;
                }
        }
    }
}

// ---------------------------------------------------------------- fused attention, K-split partials
// EXACT round-3 structure (passed on HW): 256 threads, 4 waves x 32 q-rows, 2-buf K/V,
// plain __syncthreads pipeline, swapped-QK^T 32x32, in-register softmax (T12),
// MFMA-pipe denominator (ones row). Deltas vs round 3: (1) grid 1024 — each block does
// HALF the keys (tiles gt = half*16 + t); (2) epilogue writes UNNORMALIZED bf16
// O-partials (ctx layout) + per-(bh,q) f32 denominators. k_combine merges.
__global__ __launch_bounds__(256) void k_attn_part(const unsigned short* __restrict__ Q,
                                                   const unsigned short* __restrict__ K,
                                                   const unsigned short* __restrict__ Vt,
                                                   unsigned short* __restrict__ PA,
                                                   unsigned short* __restrict__ PB,
                                                   float* __restrict__ dnA,
                                                   float* __restrict__ dnB) {
    __shared__ __align__(16) unsigned short smem[16384];   // 32KB: K dbuf | V dbuf (osc reuse)
    unsigned short* Ks = smem;           // [2][4096]
    unsigned short* Vs = smem + 8192;    // [2][4096]
    const int tid = threadIdx.x, lane = tid & 63, w = tid >> 6;
    const int hi = lane >> 5, l31 = lane & 31;

    // XCD-chunked swizzle over 1024 blocks: chunk = 128 consecutive wg per XCD (4 bh each)
    const int wg = (blockIdx.x & 7) * 128 + (blockIdx.x >> 3);
    const int bh = wg >> 5;
    const int rest = wg & 31;
    const int q0 = (rest >> 1) * 128;
    const int half = rest & 1;                  // 0: ktok 0..1023, 1: ktok 1024..2047
    const int tbase = half * 16;

    const unsigned short* qh = Q  + (size_t)bh * SQ * HD;
    const unsigned short* kh = K  + (size_t)bh * SQ * HD;
    const unsigned short* vh = Vt + (size_t)bh * HD * SQ;

    // Q^T B-fragments: lane provides col q = l31, k(d) = ks*16 + hi*8 + 0..7
    short8 qf[4];
#pragma unroll
    for (int ks = 0; ks < 4; ++ks)
        qf[ks] = *(const short8*)(qh + (size_t)(q0 + w * 32 + l31) * HD + ks * 16 + hi * 8);

    short8 ones;
#pragma unroll
    for (int i = 0; i < 8; ++i) ones[i] = (short)0x3F80;   // bf16 1.0

    f32x16 o[2] = {{0}, {0}};   // O^T partial: d = da*32 + (reg&3)+8*(reg>>2)+4*hi, q col = l31
    f32x16 od = {};             // denominator partial (colsum of P^T on the MFMA pipe)

    auto stage = [&](int t, int bi) {           // 4 global_load_lds per thread
        int gt = tbase + t;
#pragma unroll
        for (int i = 0; i < 2; ++i) {
            int u = tid + i * 256;              // row = u>>3 (0..63), chunk = u&7
            int row = u >> 3, c = u & 7;
            int cs = c ^ (row & 7);             // inverse-swizzled global source chunk
            gload16(kh + (size_t)(gt * 64 + row) * HD + cs * 8, Ks + bi * 4096 + u * 8);
            gload16(vh + (size_t)row * SQ + gt * 64 + cs * 8, Vs + bi * 4096 + u * 8);
        }
    };

    stage(0, 0);
    for (int t = 0; t < 16; ++t) {
        __syncthreads();                        // tile t landed (full fence+drain); prev reads done
        if (t + 1 < 16) stage(t + 1, (t + 1) & 1);
        const unsigned short* kb_ = Ks + (t & 1) * 4096;
        const unsigned short* vb_ = Vs + (t & 1) * 4096;

#pragma unroll
        for (int kb = 0; kb < 2; ++kb) {        // two 32-ktok strips per tile
            f32x16 s = {};
            {
                short8 kf[4];
#pragma unroll
                for (int ks = 0; ks < 4; ++ks) {
                    int row = kb * 32 + l31;
                    kf[ks] = *(const short8*)&kb_[row * 64 + (((ks * 2 + hi) ^ (row & 7)) * 8)];
                }
                __builtin_amdgcn_s_setprio(1);
#pragma unroll
                for (int ks = 0; ks < 4; ++ks) s = MFMA32(kf[ks], qf[ks], s);
                __builtin_amdgcn_s_setprio(0);
            }

            float p[16];
#pragma unroll
            for (int r = 0; r < 16; ++r) p[r] = fexp2(s[r]);

            unsigned g0 = cvtpk(p[0],  p[1]),  g1 = cvtpk(p[2],  p[3]);
            unsigned g2 = cvtpk(p[4],  p[5]),  g3 = cvtpk(p[6],  p[7]);
            unsigned g4 = cvtpk(p[8],  p[9]),  g5 = cvtpk(p[10], p[11]);
            unsigned g6 = cvtpk(p[12], p[13]), g7 = cvtpk(p[14], p[15]);
            plswap(g0, g2); plswap(g1, g3);
            plswap(g4, g6); plswap(g5, g7);
            short8 pf[2] = { pack4(g0, g1, g2, g3), pack4(g4, g5, g6, g7) };

            short8 vf[2][2];
#pragma unroll
            for (int ks2 = 0; ks2 < 2; ++ks2)
#pragma unroll
                for (int da = 0; da < 2; ++da) {
                    int row = da * 32 + l31;
                    vf[ks2][da] = *(const short8*)&vb_[row * 64 + (((kb * 4 + ks2 * 2 + hi) ^ (row & 7)) * 8)];
                }
            __builtin_amdgcn_s_setprio(1);
#pragma unroll
            for (int ks2 = 0; ks2 < 2; ++ks2) {
#pragma unroll
                for (int da = 0; da < 2; ++da)
                    o[da] = MFMA32(vf[ks2][da], pf[ks2], o[da]);
                od = MFMA32(ones, pf[ks2], od);
            }
            __builtin_amdgcn_s_setprio(0);
        }
    }

    __syncthreads();                             // staging reads done; reuse smem for O^T transpose

    unsigned short* Pout = half ? PB : PA;
    float*          dnO  = half ? dnB : dnA;

    // UNNORMALIZED partial: bf16 via osc transpose (round-3 epilogue minus the inv multiply)
    unsigned short* osc = smem + w * 2304;       // per-wave [32 q][72] ushort (144B rows)
#pragma unroll
    for (int da = 0; da < 2; ++da)
#pragma unroll
        for (int g = 0; g < 4; ++g) {
            uint2v pk;
            pk[0] = cvtpk(o[da][4 * g],     o[da][4 * g + 1]);
            pk[1] = cvtpk(o[da][4 * g + 2], o[da][4 * g + 3]);
            int d = da * 32 + 8 * g + 4 * hi;    // 4 consecutive d
            *(uint2v*)&osc[l31 * 72 + d] = pk;
        }
    __syncthreads();

    const int b = bh >> 4, h = bh & 15;
#pragma unroll
    for (int rr = 0; rr < 4; ++rr) {
        int qrow = rr * 8 + (lane >> 3), ck = lane & 7;
        int4v vv = *(const int4v*)&osc[qrow * 72 + ck * 8];
        *(int4v*)&Pout[((size_t)(b * SQ + q0 + w * 32 + qrow)) * DI + h * 64 + ck * 8] = vv;
    }
    if (hi == 0)                                 // denominator: one f32 per (bh, q)
        dnO[(size_t)bh * SQ + q0 + w * 32 + l31] = od[0];
}

// ---------------------------------------------------------------- combine partials -> ctx
// ctx[m][c] = (PA[m][c] + PB[m][c]) / (dnA[bh][q] + dnB[bh][q]); in-place on PA.
__global__ __launch_bounds__(256) void k_combine(unsigned short* __restrict__ PA,
                                                 const unsigned short* __restrict__ PB,
                                                 const float* __restrict__ dnA,
                                                 const float* __restrict__ dnB) {
    int i = blockIdx.x * 256 + threadIdx.x;      // one 16B chunk (8 bf16) per thread
    int m = i >> 7;                              // row 0..4095  (b*2048 + q)
    int ci = i & 127;                            // chunk in row; head h = ci>>3
    int q = m & (SQ - 1), b = m >> 11, h = ci >> 3;
    size_t dn_i = (size_t)(b * NH + h) * SQ + q;
    float inv = 1.0f / (dnA[dn_i] + dnB[dn_i]);
    size_t off = (size_t)m * DI + ci * 8;
    ushort4v a0 = *(const ushort4v*)(PA + off), a1 = *(const ushort4v*)(PA + off + 4);
    ushort4v b0 = *(const ushort4v*)(PB + off), b1 = *(const ushort4v*)(PB + off + 4);
    uint2v o0, o1;
    o0[0] = cvtpk((bf2f(a0[0]) + bf2f(b0[0])) * inv, (bf2f(a0[1]) + bf2f(b0[1])) * inv);
    o0[1] = cvtpk((bf2f(a0[2]) + bf2f(b0[2])) * inv, (bf2f(a0[3]) + bf2f(b0[3])) * inv);
    o1[0] = cvtpk((bf2f(a1[0]) + bf2f(b1[0])) * inv, (bf2f(a1[1]) + bf2f(b1[1])) * inv);
    o1[1] = cvtpk((bf2f(a1[2]) + bf2f(b1[2])) * inv, (bf2f(a1[3]) + bf2f(b1[3])) * inv);
    *(uint2v*)(PA + off)     = o0;
    *(uint2v*)(PA + off + 4) = o1;
}

// ---------------------------------------------------------------- launch
extern "C" void kernel_launch(void* const* d_in, const int* in_sizes, int n_in,
                              void* d_out, int out_size, void* d_ws, size_t ws_size,
                              hipStream_t stream) {
    const float* x  = (const float*)d_in[0];
    const float* Wq = (const float*)d_in[1];
    const float* Wk = (const float*)d_in[2];
    const float* Wv = (const float*)d_in[3];
    const float* Wo = (const float*)d_in[4];
    const float* bo = (const float*)d_in[5];

    char* ws = (char*)d_ws;
    unsigned short* xb   = (unsigned short*)(ws);                 //  8 MB  x bf16; REUSED as PB after QKV
    unsigned short* Wall = (unsigned short*)(ws + (8u  << 20));   //  6 MB  [Wq|Wk|Wv]^T; dn* reuse after QKV
    unsigned short* Wot  = (unsigned short*)(ws + (14u << 20));   //  2 MB  Wo^T bf16 (live to the end)
    unsigned short* Qh   = (unsigned short*)(ws + (16u << 20));   //  8 MB  queries (= x@Wk, pre-scaled)
    unsigned short* Kh   = (unsigned short*)(ws + (24u << 20));   //  8 MB  keys    (= x@Wq)
    unsigned short* Vt   = (unsigned short*)(ws + (32u << 20));   //  8 MB  values^T
    unsigned short* ctx  = (unsigned short*)(ws + (40u << 20));   //  8 MB  PA, then combined ctx (in-place)

    unsigned short* PA  = ctx;
    unsigned short* PB  = xb;                                     // dead after QKV GEMM
    float*          dnA = (float*)(ws + (8u << 20));              // 256 KB (Wall slot, dead after QKV)
    float*          dnB = (float*)(ws + (9u << 20));              // 256 KB

    k_cvt_bf16<<<2048, 256, 0, stream>>>(x, xb);
    k_transpose_w4<<<dim3(32, 32, 4), dim3(32, 8), 0, stream>>>(
        Wq, Wk, Wv, Wo, Wall, Wall + (1u << 20), Wall + (2u << 20), Wot);

    // fused QKV: keys = x@Wq (which 0), queries = x@Wk scaled (which 1), values^T = x@Wv (which 2)
    k_gemm<0><<<dim3(24, 32), 256, 0, stream>>>(xb, Wall, Kh, Qh, Vt, nullptr);

    k_attn_part<<<dim3(1024), 256, 0, stream>>>(Qh, Kh, Vt, PA, PB, dnA, dnB);
    k_combine<<<dim3(2048), 256, 0, stream>>>(PA, PB, dnA, dnB);

    k_gemm<2><<<dim3(8, 32), 256, 0, stream>>>(ctx, Wot, (unsigned short*)d_out, nullptr, nullptr, bo);
}

// Round 12
// 123.236 us; speedup vs baseline: 1.0108x; 1.0108x over previous
//
#include <hip/hip_runtime.h>
#include <math.h>

#define DI 1024   // model dim
#define SQ 2048   // sequence length
#define NB 2      // batch
#define NH 16     // heads
#define HD 64     // head dim
#define QSCALE 0.18033688f   // 0.125 * log2(e): folded into Q so softmax exp is raw v_exp_f32 (2^x)

typedef __attribute__((ext_vector_type(8))) short short8;
typedef __attribute__((ext_vector_type(4))) float f32x4;
typedef __attribute__((ext_vector_type(16))) float f32x16;
typedef __attribute__((ext_vector_type(2))) unsigned int uint2v;
typedef __attribute__((ext_vector_type(4))) int int4v;
typedef __attribute__((ext_vector_type(4))) unsigned short ushort4v;

static __device__ __forceinline__ unsigned short f2bf(float f) {
    union { float f; unsigned u; } v; v.f = f;
    unsigned r = v.u + 0x7FFFu + ((v.u >> 16) & 1u);  // RNE
    return (unsigned short)(r >> 16);
}
static __device__ __forceinline__ float bf2f(unsigned short b) {
    union { unsigned u; float f; } v; v.u = ((unsigned)b) << 16; return v.f;
}
static __device__ __forceinline__ float fexp2(float x) {
    float r; asm("v_exp_f32 %0, %1" : "=v"(r) : "v"(x)); return r;
}
static __device__ __forceinline__ unsigned cvtpk(float lo, float hi) {
    unsigned r; asm("v_cvt_pk_bf16_f32 %0, %1, %2" : "=v"(r) : "v"(lo), "v"(hi)); return r;
}
static __device__ __forceinline__ void plswap(unsigned& a, unsigned& b) {
    asm volatile("v_permlane32_swap_b32 %0, %1" : "+v"(a), "+v"(b));
}
static __device__ __forceinline__ short8 pack4(unsigned a, unsigned b, unsigned c, unsigned d) {
    union { unsigned u[4]; short8 s; } x; x.u[0] = a; x.u[1] = b; x.u[2] = c; x.u[3] = d; return x.s;
}

typedef __attribute__((address_space(1))) const unsigned int gas_uint;
typedef __attribute__((address_space(3))) unsigned int las_uint;
static __device__ __forceinline__ void gload16(const void* g, void* l) {
    __builtin_amdgcn_global_load_lds((gas_uint*)g, (las_uint*)l, 16, 0, 0);
}
#define RAW_BARRIER() do { __builtin_amdgcn_s_barrier(); \
                           __builtin_amdgcn_sched_barrier(0); } while (0)
#define WAIT_VM4()  do { asm volatile("s_waitcnt vmcnt(4)" ::: "memory"); \
                         __builtin_amdgcn_sched_barrier(0); } while (0)
#define WAIT_VM0()  do { asm volatile("s_waitcnt vmcnt(0)" ::: "memory"); \
                         __builtin_amdgcn_sched_barrier(0); } while (0)

#define MFMA16(a, b, c) __builtin_amdgcn_mfma_f32_16x16x32_bf16(a, b, c, 0, 0, 0)
#define MFMA32(a, b, c) __builtin_amdgcn_mfma_f32_32x32x16_bf16(a, b, c, 0, 0, 0)

// ---------------------------------------------------------------- cvt x -> bf16
__global__ __launch_bounds__(256) void k_cvt_bf16(const float* __restrict__ src,
                                                  unsigned short* __restrict__ dst) {
    int i = blockIdx.x * 256 + threadIdx.x;     // 8 floats / thread
    const f32x4* s4 = (const f32x4*)src + (size_t)i * 2;
    f32x4 a = s4[0], b = s4[1];
    ushort4v o0, o1;
    o0[0] = f2bf(a[0]); o0[1] = f2bf(a[1]); o0[2] = f2bf(a[2]); o0[3] = f2bf(a[3]);
    o1[0] = f2bf(b[0]); o1[1] = f2bf(b[1]); o1[2] = f2bf(b[2]); o1[3] = f2bf(b[3]);
    *(ushort4v*)(dst + (size_t)i * 8)     = o0;
    *(ushort4v*)(dst + (size_t)i * 8 + 4) = o1;
}

// ------------------------------------- 4x: W [K][N] f32 -> Wt [N][K] bf16 (one dispatch)
__global__ __launch_bounds__(256) void k_transpose_w4(const float* __restrict__ W0, const float* __restrict__ W1,
                                                      const float* __restrict__ W2, const float* __restrict__ W3,
                                                      unsigned short* __restrict__ T0, unsigned short* __restrict__ T1,
                                                      unsigned short* __restrict__ T2, unsigned short* __restrict__ T3) {
    const float* W; unsigned short* T;
    switch (blockIdx.z) {
        case 0: W = W0; T = T0; break;
        case 1: W = W1; T = T1; break;
        case 2: W = W2; T = T2; break;
        default: W = W3; T = T3; break;
    }
    __shared__ float t[32][33];
    int tx = threadIdx.x, ty = threadIdx.y;     // block (32,8)
    int n0 = blockIdx.x * 32, k0 = blockIdx.y * 32;
#pragma unroll
    for (int j = 0; j < 32; j += 8) t[ty + j][tx] = W[(size_t)(k0 + ty + j) * DI + n0 + tx];
    __syncthreads();
#pragma unroll
    for (int j = 0; j < 32; j += 8)
        T[(size_t)(n0 + ty + j) * DI + k0 + tx] = f2bf(t[tx][ty + j]);
}

// ---------------------------------------------------------------- NT GEMM (m97 + counted vmcnt, 3-buf)
// MODE 0: fused QKV. Bt = [3*1024][1024]; which = tn>>3 routes to oK / oQ(scaled) / oV(transposed).
// MODE 2: f32 out + bias (final projection), C = oK as float*.
template <int MODE>
__global__ __launch_bounds__(256) void k_gemm(const unsigned short* __restrict__ A,
                                              const unsigned short* __restrict__ Bt,
                                              unsigned short* __restrict__ oK,
                                              unsigned short* __restrict__ oQ,
                                              unsigned short* __restrict__ oV,
                                              const float* __restrict__ bias) {
    __shared__ __align__(16) unsigned short As[3][128 * 32];   // linear, 64B rows, 3-buf
    __shared__ __align__(16) unsigned short Bs[3][128 * 32];
    const int tid = threadIdx.x, lane = tid & 63, w = tid >> 6;
    const int wr = w >> 1, wc = w & 1;
    const int tm = blockIdx.y, tn = blockIdx.x;
    const unsigned short* Abase = A  + (size_t)tm * 128 * DI;
    const unsigned short* Bbase = Bt + (size_t)tn * 128 * DI;

    auto stage = [&](int kt, int bi) {          // 4 global_load_lds per thread
#pragma unroll
        for (int i = 0; i < 2; ++i) {
            int u = tid + i * 256;              // 0..511 : row = u>>2, 16B seg = u&3
            int row = u >> 2, c8 = (u & 3) * 8;
            gload16(Abase + (size_t)row * DI + kt * 32 + c8, &As[bi][u * 8]);
            gload16(Bbase + (size_t)row * DI + kt * 32 + c8, &Bs[bi][u * 8]);
        }
    };

    f32x4 acc[4][4] = {};
    stage(0, 0);
    for (int kt = 0; kt < DI / 32; ++kt) {
        if (kt + 1 < DI / 32) { stage(kt + 1, (kt + 1) % 3); WAIT_VM4(); }
        else                  { WAIT_VM0(); }
        RAW_BARRIER();                          // all waves' tile-kt loads landed
        const int bi = kt % 3;
        short8 af[4], bf[4];
#pragma unroll
        for (int mi = 0; mi < 4; ++mi)
            af[mi] = *(const short8*)&As[bi][(wr * 64 + mi * 16 + (lane & 15)) * 32 + (lane >> 4) * 8];
#pragma unroll
        for (int ni = 0; ni < 4; ++ni)
            bf[ni] = *(const short8*)&Bs[bi][(wc * 64 + ni * 16 + (lane & 15)) * 32 + (lane >> 4) * 8];
        __builtin_amdgcn_s_setprio(1);
#pragma unroll
        for (int mi = 0; mi < 4; ++mi)
#pragma unroll
            for (int ni = 0; ni < 4; ++ni)
                acc[mi][ni] = MFMA16(af[mi], bf[ni], acc[mi][ni]);
        __builtin_amdgcn_s_setprio(0);
    }

    if (MODE == 2) {
        float bv[4];
#pragma unroll
        for (int ni = 0; ni < 4; ++ni) bv[ni] = bias[tn * 128 + wc * 64 + ni * 16 + (lane & 15)];
        float* Co = (float*)oK;
#pragma unroll
        for (int mi = 0; mi < 4; ++mi)
#pragma unroll
            for (int ni = 0; ni < 4; ++ni)
#pragma unroll
                for (int j = 0; j < 4; ++j) {
                    int m = tm * 128 + wr * 64 + mi * 16 + (lane >> 4) * 4 + j;
                    int n = tn * 128 + wc * 64 + ni * 16 + (lane & 15);
                    Co[(size_t)m * DI + n] = acc[mi][ni][j] + bv[ni];
                }
    } else {
        const int which = tn >> 3;                  // 0:K  1:Q(scaled)  2:V(transposed)
        if (which < 2) {
            unsigned short* Co = which ? oQ : oK;
            const float scl = which ? QSCALE : 1.0f;
#pragma unroll
            for (int mi = 0; mi < 4; ++mi)
#pragma unroll
                for (int ni = 0; ni < 4; ++ni)
#pragma unroll
                    for (int j = 0; j < 4; ++j) {
                        int m = tm * 128 + wr * 64 + mi * 16 + (lane >> 4) * 4 + j;
                        int n = (tn & 7) * 128 + wc * 64 + ni * 16 + (lane & 15);
                        Co[(((size_t)(m >> 11) * NH + (n >> 6)) * SQ + (m & 2047)) * HD + (n & 63)] =
                            f2bf(acc[mi][ni][j] * scl);
                    }
        } else {                                    // V^T: [B][H][D][S], 4 S-contig per lane
#pragma unroll
            for (int mi = 0; mi < 4; ++mi)
#pragma unroll
                for (int ni = 0; ni < 4; ++ni) {
                    uint2v pk;
                    pk[0] = cvtpk(acc[mi][ni][0], acc[mi][ni][1]);
                    pk[1] = cvtpk(acc[mi][ni][2], acc[mi][ni][3]);
                    int m = tm * 128 + wr * 64 + mi * 16 + (lane >> 4) * 4;
                    int n = (tn & 7) * 128 + wc * 64 + ni * 16 + (lane & 15);
                    *(uint2v*)&oV[(((size_t)(m >> 11) * NH + (n >> 6)) * HD + (n & 63)) * SQ + (m & 2047)] = pk;
                }
        }
    }
}

// ---------------------------------------------------------------- fused attention, K-split partials
// Round-10 structure (passed on HW). SINGLE delta vs round 10: the ones-row MFMA
// denominator (16-reg od) is replaced by the round-3-proven p[16] + ls VALU
// accumulator + __shfl_xor(ls,32) reduction. This frees 16 acc registers so total
// (V+A)GPR fits 4 waves/SIMD naturally (round 10 ran 2 sequential grid-halves at
// 2 blocks/CU — register-capped). No launch_bounds override (round-11 suspect).
__global__ __launch_bounds__(256) void k_attn_part(const unsigned short* __restrict__ Q,
                                                   const unsigned short* __restrict__ K,
                                                   const unsigned short* __restrict__ Vt,
                                                   unsigned short* __restrict__ PA,
                                                   unsigned short* __restrict__ PB,
                                                   float* __restrict__ dnA,
                                                   float* __restrict__ dnB) {
    __shared__ __align__(16) unsigned short smem[16384];   // 32KB: K dbuf | V dbuf (osc reuse)
    unsigned short* Ks = smem;           // [2][4096]
    unsigned short* Vs = smem + 8192;    // [2][4096]
    const int tid = threadIdx.x, lane = tid & 63, w = tid >> 6;
    const int hi = lane >> 5, l31 = lane & 31;

    // XCD-chunked swizzle over 1024 blocks: chunk = 128 consecutive wg per XCD (4 bh each)
    const int wg = (blockIdx.x & 7) * 128 + (blockIdx.x >> 3);
    const int bh = wg >> 5;
    const int rest = wg & 31;
    const int q0 = (rest >> 1) * 128;
    const int half = rest & 1;                  // 0: ktok 0..1023, 1: ktok 1024..2047
    const int tbase = half * 16;

    const unsigned short* qh = Q  + (size_t)bh * SQ * HD;
    const unsigned short* kh = K  + (size_t)bh * SQ * HD;
    const unsigned short* vh = Vt + (size_t)bh * HD * SQ;

    // Q^T B-fragments: lane provides col q = l31, k(d) = ks*16 + hi*8 + 0..7
    short8 qf[4];
#pragma unroll
    for (int ks = 0; ks < 4; ++ks)
        qf[ks] = *(const short8*)(qh + (size_t)(q0 + w * 32 + l31) * HD + ks * 16 + hi * 8);

    f32x16 o[2] = {{0}, {0}};   // O^T partial: d = da*32 + (reg&3)+8*(reg>>2)+4*hi, q col = l31
    float ls = 0.0f;            // denominator partial: this lane's 16 rows/strip for q = l31

    auto stage = [&](int t, int bi) {           // 4 global_load_lds per thread
        int gt = tbase + t;
#pragma unroll
        for (int i = 0; i < 2; ++i) {
            int u = tid + i * 256;              // row = u>>3 (0..63), chunk = u&7
            int row = u >> 3, c = u & 7;
            int cs = c ^ (row & 7);             // inverse-swizzled global source chunk
            gload16(kh + (size_t)(gt * 64 + row) * HD + cs * 8, Ks + bi * 4096 + u * 8);
            gload16(vh + (size_t)row * SQ + gt * 64 + cs * 8, Vs + bi * 4096 + u * 8);
        }
    };

    stage(0, 0);
    for (int t = 0; t < 16; ++t) {
        __syncthreads();                        // tile t landed (full fence+drain); prev reads done
        if (t + 1 < 16) stage(t + 1, (t + 1) & 1);
        const unsigned short* kb_ = Ks + (t & 1) * 4096;
        const unsigned short* vb_ = Vs + (t & 1) * 4096;

#pragma unroll
        for (int kb = 0; kb < 2; ++kb) {        // two 32-ktok strips per tile
            f32x16 s = {};
            {
                short8 kf[4];
#pragma unroll
                for (int ks = 0; ks < 4; ++ks) {
                    int row = kb * 32 + l31;
                    kf[ks] = *(const short8*)&kb_[row * 64 + (((ks * 2 + hi) ^ (row & 7)) * 8)];
                }
                __builtin_amdgcn_s_setprio(1);
#pragma unroll
                for (int ks = 0; ks < 4; ++ks) s = MFMA32(kf[ks], qf[ks], s);
                __builtin_amdgcn_s_setprio(0);
            }

            // softmax: p = 2^s (Q pre-scaled); lane-local denominator partials (round-3 idiom)
            float p[16];
#pragma unroll
            for (int r = 0; r < 16; ++r) { p[r] = fexp2(s[r]); ls += p[r]; }

            // pack P^T to bf16 PV B-fragments: cvt_pk pairs + permlane32_swap (T12)
            unsigned g0 = cvtpk(p[0],  p[1]),  g1 = cvtpk(p[2],  p[3]);
            unsigned g2 = cvtpk(p[4],  p[5]),  g3 = cvtpk(p[6],  p[7]);
            unsigned g4 = cvtpk(p[8],  p[9]),  g5 = cvtpk(p[10], p[11]);
            unsigned g6 = cvtpk(p[12], p[13]), g7 = cvtpk(p[14], p[15]);
            plswap(g0, g2); plswap(g1, g3);
            plswap(g4, g6); plswap(g5, g7);
            short8 pf[2] = { pack4(g0, g1, g2, g3), pack4(g4, g5, g6, g7) };

            // O^T += V^T @ P^T
            short8 vf[2][2];
#pragma unroll
            for (int ks2 = 0; ks2 < 2; ++ks2)
#pragma unroll
                for (int da = 0; da < 2; ++da) {
                    int row = da * 32 + l31;
                    vf[ks2][da] = *(const short8*)&vb_[row * 64 + (((kb * 4 + ks2 * 2 + hi) ^ (row & 7)) * 8)];
                }
            __builtin_amdgcn_s_setprio(1);
#pragma unroll
            for (int ks2 = 0; ks2 < 2; ++ks2)
#pragma unroll
                for (int da = 0; da < 2; ++da)
                    o[da] = MFMA32(vf[ks2][da], pf[ks2], o[da]);
            __builtin_amdgcn_s_setprio(0);
        }
    }

    __syncthreads();                             // staging reads done; reuse smem for O^T transpose

    float dsum = ls + __shfl_xor(ls, 32);        // combine lane-half partials: full denom for q = l31

    unsigned short* Pout = half ? PB : PA;
    float*          dnO  = half ? dnB : dnA;

    // UNNORMALIZED partial: bf16 via osc transpose
    unsigned short* osc = smem + w * 2304;       // per-wave [32 q][72] ushort (144B rows)
#pragma unroll
    for (int da = 0; da < 2; ++da)
#pragma unroll
        for (int g = 0; g < 4; ++g) {
            uint2v pk;
            pk[0] = cvtpk(o[da][4 * g],     o[da][4 * g + 1]);
            pk[1] = cvtpk(o[da][4 * g + 2], o[da][4 * g + 3]);
            int d = da * 32 + 8 * g + 4 * hi;    // 4 consecutive d
            *(uint2v*)&osc[l31 * 72 + d] = pk;
        }
    __syncthreads();

    const int b = bh >> 4, h = bh & 15;
#pragma unroll
    for (int rr = 0; rr < 4; ++rr) {
        int qrow = rr * 8 + (lane >> 3), ck = lane & 7;
        int4v vv = *(const int4v*)&osc[qrow * 72 + ck * 8];
        *(int4v*)&Pout[((size_t)(b * SQ + q0 + w * 32 + qrow)) * DI + h * 64 + ck * 8] = vv;
    }
    if (hi == 0)                                 // denominator: one f32 per (bh, q)
        dnO[(size_t)bh * SQ + q0 + w * 32 + l31] = dsum;
}

// ---------------------------------------------------------------- combine partials -> ctx
// ctx[m][c] = (PA[m][c] + PB[m][c]) / (dnA[bh][q] + dnB[bh][q]); in-place on PA.
__global__ __launch_bounds__(256) void k_combine(unsigned short* __restrict__ PA,
                                                 const unsigned short* __restrict__ PB,
                                                 const float* __restrict__ dnA,
                                                 const float* __restrict__ dnB) {
    int i = blockIdx.x * 256 + threadIdx.x;      // one 16B chunk (8 bf16) per thread
    int m = i >> 7;                              // row 0..4095  (b*2048 + q)
    int ci = i & 127;                            // chunk in row; head h = ci>>3
    int q = m & (SQ - 1), b = m >> 11, h = ci >> 3;
    size_t dn_i = (size_t)(b * NH + h) * SQ + q;
    float inv = 1.0f / (dnA[dn_i] + dnB[dn_i]);
    size_t off = (size_t)m * DI + ci * 8;
    ushort4v a0 = *(const ushort4v*)(PA + off), a1 = *(const ushort4v*)(PA + off + 4);
    ushort4v b0 = *(const ushort4v*)(PB + off), b1 = *(const ushort4v*)(PB + off + 4);
    uint2v o0, o1;
    o0[0] = cvtpk((bf2f(a0[0]) + bf2f(b0[0])) * inv, (bf2f(a0[1]) + bf2f(b0[1])) * inv);
    o0[1] = cvtpk((bf2f(a0[2]) + bf2f(b0[2])) * inv, (bf2f(a0[3]) + bf2f(b0[3])) * inv);
    o1[0] = cvtpk((bf2f(a1[0]) + bf2f(b1[0])) * inv, (bf2f(a1[1]) + bf2f(b1[1])) * inv);
    o1[1] = cvtpk((bf2f(a1[2]) + bf2f(b1[2])) * inv, (bf2f(a1[3]) + bf2f(b1[3])) * inv);
    *(uint2v*)(PA + off)     = o0;
    *(uint2v*)(PA + off + 4) = o1;
}

// ---------------------------------------------------------------- launch
extern "C" void kernel_launch(void* const* d_in, const int* in_sizes, int n_in,
                              void* d_out, int out_size, void* d_ws, size_t ws_size,
                              hipStream_t stream) {
    const float* x  = (const float*)d_in[0];
    const float* Wq = (const float*)d_in[1];
    const float* Wk = (const float*)d_in[2];
    const float* Wv = (const float*)d_in[3];
    const float* Wo = (const float*)d_in[4];
    const float* bo = (const float*)d_in[5];

    char* ws = (char*)d_ws;
    unsigned short* xb   = (unsigned short*)(ws);                 //  8 MB  x bf16; REUSED as PB after QKV
    unsigned short* Wall = (unsigned short*)(ws + (8u  << 20));   //  6 MB  [Wq|Wk|Wv]^T; dn* reuse after QKV
    unsigned short* Wot  = (unsigned short*)(ws + (14u << 20));   //  2 MB  Wo^T bf16 (live to the end)
    unsigned short* Qh   = (unsigned short*)(ws + (16u << 20));   //  8 MB  queries (= x@Wk, pre-scaled)
    unsigned short* Kh   = (unsigned short*)(ws + (24u << 20));   //  8 MB  keys    (= x@Wq)
    unsigned short* Vt   = (unsigned short*)(ws + (32u << 20));   //  8 MB  values^T
    unsigned short* ctx  = (unsigned short*)(ws + (40u << 20));   //  8 MB  PA, then combined ctx (in-place)

    unsigned short* PA  = ctx;
    unsigned short* PB  = xb;                                     // dead after QKV GEMM
    float*          dnA = (float*)(ws + (8u << 20));              // 256 KB (Wall slot, dead after QKV)
    float*          dnB = (float*)(ws + (9u << 20));              // 256 KB

    k_cvt_bf16<<<2048, 256, 0, stream>>>(x, xb);
    k_transpose_w4<<<dim3(32, 32, 4), dim3(32, 8), 0, stream>>>(
        Wq, Wk, Wv, Wo, Wall, Wall + (1u << 20), Wall + (2u << 20), Wot);

    // fused QKV: keys = x@Wq (which 0), queries = x@Wk scaled (which 1), values^T = x@Wv (which 2)
    k_gemm<0><<<dim3(24, 32), 256, 0, stream>>>(xb, Wall, Kh, Qh, Vt, nullptr);

    k_attn_part<<<dim3(1024), 256, 0, stream>>>(Qh, Kh, Vt, PA, PB, dnA, dnB);
    k_combine<<<dim3(2048), 256, 0, stream>>>(PA, PB, dnA, dnB);

    k_gemm<2><<<dim3(8, 32), 256, 0, stream>>>(ctx, Wot, (unsigned short*)d_out, nullptr, nullptr, bo);
}